// Round 6
// baseline (103.141 us; speedup 1.0000x reference)
//
#include <hip/hip_runtime.h>

// PhobiaLoss: YOLO-style loss over (B=256, 52, 52, 20) fp32 tensors -> scalar.
// Round 6: single-dispatch. R3/R4/R5 all ~27us with three different staging
// structures -> staging isn't the limiter; ~4-5us of the total is the second
// kernel's launch + 1-block dispatch latency. Fold the final reduction into
// the main kernel via the last-block-done pattern (store partial, threadfence,
// device-scope counter; last block acquires and reduces 2704 partials).
// Deterministic: final sum is a fixed ascending loop whichever block is last.

constexpr int   kB        = 256;
constexpr int   kGrid     = 52;
constexpr int   kCells    = kB * kGrid * kGrid;   // 692224 = 2704 * 256 exactly
constexpr int   kBlocks   = kCells / 256;         // 2704
constexpr float kAlpha    = 0.25f;
constexpr float kLamCoord = 5.0f;

#define AS1(p) ((const __attribute__((address_space(1))) void*)(p))
#define AS3(p) ((__attribute__((address_space(3))) void*)(p))

__global__ __launch_bounds__(256) void phobia_main_kernel(
    const float4* __restrict__ pred4,
    const float4* __restrict__ tgt4,
    float4* __restrict__ part,        // part[block] = {coord, conf, cls, nobj}
    unsigned*  __restrict__ cnt,      // zeroed per launch
    float* __restrict__ out)
{
    // Per-wave slices: lds[w][0..320) = pred, lds[w][320..640) = tgt.
    __shared__ float4 lds[4][640];   // 40960 B exactly
    __shared__ float  sred[4][4];
    __shared__ int    isLast;

    const int tid  = threadIdx.x;
    const int wave = tid >> 6;
    const int lane = tid & 63;
    // This wave's 64 cells start at global float4 index:
    const size_t base4 = (size_t)blockIdx.x * 1280 + (size_t)wave * 320;

    // 10 direct global->LDS dwordx4 loads, all wave-local (1 KiB each, coalesced).
    #pragma unroll
    for (int k = 0; k < 5; ++k) {
        __builtin_amdgcn_global_load_lds(AS1(pred4 + base4 + k * 64 + lane),
                                         AS3(&lds[wave][k * 64]), 16, 0, 0);
        __builtin_amdgcn_global_load_lds(AS1(tgt4  + base4 + k * 64 + lane),
                                         AS3(&lds[wave][320 + k * 64]), 16, 0, 0);
    }
    // Wait for OWN loads only; waves slip freely (no block barrier here).
    asm volatile("s_waitcnt vmcnt(0)" ::: "memory");
    __builtin_amdgcn_sched_barrier(0);

    // Gather this lane's cell: stride-5 float4s -> all 8 bank-quads, conflict-free.
    const float4 P0 = lds[wave][lane * 5 + 0], P1 = lds[wave][lane * 5 + 1];
    const float4 P2 = lds[wave][lane * 5 + 2], P3 = lds[wave][lane * 5 + 3];
    const float4 T0 = lds[wave][320 + lane * 5 + 0], T1 = lds[wave][320 + lane * 5 + 1];
    const float4 T2 = lds[wave][320 + lane * 5 + 2], T3 = lds[wave][320 + lane * 5 + 3];

    const float p[16] = {P0.x, P0.y, P0.z, P0.w,  P1.x, P1.y, P1.z, P1.w,
                         P2.x, P2.y, P2.z, P2.w,  P3.x, P3.y, P3.z, P3.w};
    const float t[16] = {T0.x, T0.y, T0.z, T0.w,  T1.x, T1.y, T1.z, T1.w,
                         T2.x, T2.y, T2.z, T2.w,  T3.x, T3.y, T3.z, T3.w};

    float coord = 0.f, conf = 0.f;
    float obj_count = 0.f;
    #pragma unroll
    for (int n = 0; n < 2; ++n) {
        const int b5    = n * 5;
        const float l   = p[b5 + 4];      // conf logit
        const float tc  = t[b5 + 4];      // conf target
        const float has = (tc > 0.5f) ? 1.f : 0.f;

        float sq = 0.f;
        #pragma unroll
        for (int k = 0; k < 4; ++k) {
            const float d = p[b5 + k] - t[b5 + k];
            sq += d * d;
        }
        coord += has * sq;

        // focal BCE on confidence
        const float ce = fmaxf(l, 0.f) - l * tc + log1pf(__expf(-fabsf(l)));
        const float s  = 1.f / (1.f + __expf(-l));
        const float pt = s * tc + (1.f - s) * (1.f - tc);
        const float at = kAlpha * tc + (1.f - kAlpha) * (1.f - tc);
        const float om = 1.f - pt;
        conf += at * om * om * ce;

        obj_count += has;
    }

    // class NLL: argmax of target channels 10..14 (strict > = first-max),
    // carry the matching pred logit so all register indices stay static.
    float bv = t[10], pv = p[10];
    if (t[11] > bv) { bv = t[11]; pv = p[11]; }
    if (t[12] > bv) { bv = t[12]; pv = p[12]; }
    if (t[13] > bv) { bv = t[13]; pv = p[13]; }
    if (t[14] > bv) { bv = t[14]; pv = p[14]; }

    const float m  = fmaxf(fmaxf(fmaxf(p[10], p[11]), fmaxf(p[12], p[13])), p[14]);
    const float se = __expf(p[10] - m) + __expf(p[11] - m) + __expf(p[12] - m)
                   + __expf(p[13] - m) + __expf(p[14] - m);
    float cls  = obj_count * (__logf(se) + m - pv);
    float nobj = obj_count;

    // Wave-level reduce (64 lanes)
    #pragma unroll
    for (int off = 32; off >= 1; off >>= 1) {
        coord += __shfl_down(coord, off);
        conf  += __shfl_down(conf,  off);
        cls   += __shfl_down(cls,   off);
        nobj  += __shfl_down(nobj,  off);
    }

    if (lane == 0) {
        sred[wave][0] = coord; sred[wave][1] = conf;
        sred[wave][2] = cls;   sred[wave][3] = nobj;
    }
    __syncthreads();

    if (tid == 0) {
        float4 o;
        o.x = sred[0][0] + sred[1][0] + sred[2][0] + sred[3][0];
        o.y = sred[0][1] + sred[1][1] + sred[2][1] + sred[3][1];
        o.z = sred[0][2] + sred[1][2] + sred[2][2] + sred[3][2];
        o.w = sred[0][3] + sred[1][3] + sred[2][3] + sred[3][3];
        part[blockIdx.x] = o;            // distinct address: no contention
        __threadfence();                 // release partial before signaling
        const unsigned old = atomicAdd(cnt, 1u);
        isLast = (old == (unsigned)(kBlocks - 1)) ? 1 : 0;
    }
    __syncthreads();

    if (isLast) {
        // This block saw all other blocks' releases; acquire then reduce.
        __threadfence();
        float c0 = 0.f, c1 = 0.f, c2 = 0.f, c3 = 0.f;
        for (int i = tid; i < kBlocks; i += 256) {
            const float4 v = part[i];
            c0 += v.x; c1 += v.y; c2 += v.z; c3 += v.w;
        }
        #pragma unroll
        for (int off = 32; off >= 1; off >>= 1) {
            c0 += __shfl_down(c0, off);
            c1 += __shfl_down(c1, off);
            c2 += __shfl_down(c2, off);
            c3 += __shfl_down(c3, off);
        }
        if (lane == 0) {
            sred[wave][0] = c0; sred[wave][1] = c1;
            sred[wave][2] = c2; sred[wave][3] = c3;
        }
        __syncthreads();
        if (tid == 0) {
            const float coord2 = sred[0][0] + sred[1][0] + sred[2][0] + sred[3][0];
            const float conf2  = sred[0][1] + sred[1][1] + sred[2][1] + sred[3][1];
            const float cls2   = sred[0][2] + sred[1][2] + sred[2][2] + sred[3][2];
            const float nobj2  = sred[0][3] + sred[1][3] + sred[2][3] + sred[3][3];
            out[0] = kLamCoord * (coord2 / (float)kB)
                   + (conf2 / (float)kB)
                   + cls2 / fmaxf(nobj2, 1.f);
        }
    }
}

extern "C" void kernel_launch(void* const* d_in, const int* in_sizes, int n_in,
                              void* d_out, int out_size, void* d_ws, size_t ws_size,
                              hipStream_t stream) {
    const float4* pred4 = (const float4*)d_in[0];
    const float4* tgt4  = (const float4*)d_in[1];
    float4*   part = (float4*)d_ws;                              // 2704 * 16 B
    unsigned* cnt  = (unsigned*)((char*)d_ws + kBlocks * 16);    // 4 B counter
    float* out = (float*)d_out;

    hipMemsetAsync(cnt, 0, sizeof(unsigned), stream);
    phobia_main_kernel<<<kBlocks, 256, 0, stream>>>(pred4, tgt4, part, cnt, out);
}

// Round 7
// 26.570 us; speedup vs baseline: 3.8818x; 3.8818x over previous
//
#include <hip/hip_runtime.h>

// PhobiaLoss: YOLO-style loss over (B=256, 52, 52, 20) fp32 tensors -> scalar.
// Round 7: persistent waves + per-wave double-buffered LDS streaming.
//  - R6 post-mortem: per-block __threadfence + contended atomic re-created the
//    serialization wall (103us). Reverted to two dispatches (no fences).
//  - R3/R4/R5 all ~27us: one-shot waves leave the memory pipe idle during
//    compute/drain/relaunch. Now 512 resident blocks (2/CU at exactly 80KB
//    LDS), 2048 waves grid-stride over 10816 64-cell chunks with double
//    buffering: issue next chunk's 10 global_load_lds, s_waitcnt vmcnt(10)
//    (counted -- never drain to 0 mid-loop), compute current. Continuous
//    memory issue per wave.

constexpr int   kB        = 256;
constexpr int   kGrid     = 52;
constexpr int   kCells    = kB * kGrid * kGrid;   // 692224
constexpr int   kChunks   = kCells / 64;          // 10816 64-cell wave-chunks
constexpr int   kBlocksM  = 512;                  // 2 blocks/CU, all resident
constexpr int   kWaves    = kBlocksM * 4;         // 2048 persistent waves
constexpr float kAlpha    = 0.25f;
constexpr float kLamCoord = 5.0f;

#define AS1(p) ((const __attribute__((address_space(1))) void*)(p))
#define AS3(p) ((__attribute__((address_space(3))) void*)(p))

__device__ __forceinline__ void issue_chunk_loads(const float4* __restrict__ pred4,
                                                  const float4* __restrict__ tgt4,
                                                  int chunk, float4* dst, int lane)
{
    const size_t b4 = (size_t)chunk * 320;
    #pragma unroll
    for (int k = 0; k < 5; ++k) {
        __builtin_amdgcn_global_load_lds(AS1(pred4 + b4 + k * 64 + lane),
                                         AS3(dst + k * 64), 16, 0, 0);
        __builtin_amdgcn_global_load_lds(AS1(tgt4  + b4 + k * 64 + lane),
                                         AS3(dst + 320 + k * 64), 16, 0, 0);
    }
}

__global__ __launch_bounds__(256) void phobia_main_kernel(
    const float4* __restrict__ pred4,
    const float4* __restrict__ tgt4,
    float4* __restrict__ part)   // part[block] = {coord, conf, cls, nobj}
{
    // Per-wave double buffer: [wave][buf][0..320)=pred, [320..640)=tgt.
    __shared__ float4 lds[4][2][640];   // 81920 B exactly (160KB/CU / 2 blocks)

    const int tid   = threadIdx.x;
    const int wave  = tid >> 6;
    const int lane  = tid & 63;
    const int gwave = blockIdx.x * 4 + wave;

    float coord = 0.f, conf = 0.f, cls = 0.f, nobj = 0.f;

    int cur = gwave;          // every wave has >=5 chunks (2048*5 < 10816)
    int buf = 0;
    issue_chunk_loads(pred4, tgt4, cur, &lds[wave][0][0], lane);
    int next = cur + kWaves;

    while (cur < kChunks) {
        if (next < kChunks) {
            issue_chunk_loads(pred4, tgt4, next, &lds[wave][buf ^ 1][0], lane);
            // Counted wait: cur's 10 loads done, next's 10 stay in flight.
            asm volatile("s_waitcnt vmcnt(10)" ::: "memory");
        } else {
            asm volatile("s_waitcnt vmcnt(0)" ::: "memory");
        }
        __builtin_amdgcn_sched_barrier(0);

        const float4* L = &lds[wave][buf][0];
        // Stride-5 float4 gather -> all 8 bank-quads, conflict-free.
        const float4 P0 = L[lane * 5 + 0], P1 = L[lane * 5 + 1];
        const float4 P2 = L[lane * 5 + 2], P3 = L[lane * 5 + 3];
        const float4 T0 = L[320 + lane * 5 + 0], T1 = L[320 + lane * 5 + 1];
        const float4 T2 = L[320 + lane * 5 + 2], T3 = L[320 + lane * 5 + 3];

        const float p[16] = {P0.x, P0.y, P0.z, P0.w,  P1.x, P1.y, P1.z, P1.w,
                             P2.x, P2.y, P2.z, P2.w,  P3.x, P3.y, P3.z, P3.w};
        const float t[16] = {T0.x, T0.y, T0.z, T0.w,  T1.x, T1.y, T1.z, T1.w,
                             T2.x, T2.y, T2.z, T2.w,  T3.x, T3.y, T3.z, T3.w};

        float obj_count = 0.f;
        #pragma unroll
        for (int n = 0; n < 2; ++n) {
            const int b5    = n * 5;
            const float l   = p[b5 + 4];      // conf logit
            const float tc  = t[b5 + 4];      // conf target
            const float has = (tc > 0.5f) ? 1.f : 0.f;

            float sq = 0.f;
            #pragma unroll
            for (int k = 0; k < 4; ++k) {
                const float d = p[b5 + k] - t[b5 + k];
                sq += d * d;
            }
            coord += has * sq;

            // focal BCE on confidence
            const float ce = fmaxf(l, 0.f) - l * tc + log1pf(__expf(-fabsf(l)));
            const float s  = 1.f / (1.f + __expf(-l));
            const float pt = s * tc + (1.f - s) * (1.f - tc);
            const float at = kAlpha * tc + (1.f - kAlpha) * (1.f - tc);
            const float om = 1.f - pt;
            conf += at * om * om * ce;

            obj_count += has;
        }
        nobj += obj_count;

        // class NLL: argmax of target channels 10..14 (strict > = first-max),
        // carry the matching pred logit so register indices stay static.
        float bv = t[10], pv = p[10];
        if (t[11] > bv) { bv = t[11]; pv = p[11]; }
        if (t[12] > bv) { bv = t[12]; pv = p[12]; }
        if (t[13] > bv) { bv = t[13]; pv = p[13]; }
        if (t[14] > bv) { bv = t[14]; pv = p[14]; }

        const float m  = fmaxf(fmaxf(fmaxf(p[10], p[11]), fmaxf(p[12], p[13])), p[14]);
        const float se = __expf(p[10] - m) + __expf(p[11] - m) + __expf(p[12] - m)
                       + __expf(p[13] - m) + __expf(p[14] - m);
        cls += obj_count * (__logf(se) + m - pv);

        cur = next; next += kWaves; buf ^= 1;
    }

    // Wave-level reduce (64 lanes)
    #pragma unroll
    for (int off = 32; off >= 1; off >>= 1) {
        coord += __shfl_down(coord, off);
        conf  += __shfl_down(conf,  off);
        cls   += __shfl_down(cls,   off);
        nobj  += __shfl_down(nobj,  off);
    }

    // Reuse this wave's own LDS slice for its partial (loads all drained).
    if (lane == 0) {
        float4 o; o.x = coord; o.y = conf; o.z = cls; o.w = nobj;
        lds[wave][0][0] = o;
    }
    __syncthreads();
    if (tid == 0) {
        const float4 a = lds[0][0][0], b = lds[1][0][0];
        const float4 c = lds[2][0][0], d = lds[3][0][0];
        float4 o;
        o.x = a.x + b.x + c.x + d.x;
        o.y = a.y + b.y + c.y + d.y;
        o.z = a.z + b.z + c.z + d.z;
        o.w = a.w + b.w + c.w + d.w;
        part[blockIdx.x] = o;   // distinct address per block: no contention
    }
}

__global__ __launch_bounds__(256) void phobia_reduce_kernel(
    const float4* __restrict__ part, float* __restrict__ out)
{
    const int tid = threadIdx.x;
    float c0 = 0.f, c1 = 0.f, c2 = 0.f, c3 = 0.f;
    #pragma unroll
    for (int r = 0; r < kBlocksM / 256; ++r) {
        const float4 v = part[r * 256 + tid];
        c0 += v.x; c1 += v.y; c2 += v.z; c3 += v.w;
    }
    #pragma unroll
    for (int off = 32; off >= 1; off >>= 1) {
        c0 += __shfl_down(c0, off);
        c1 += __shfl_down(c1, off);
        c2 += __shfl_down(c2, off);
        c3 += __shfl_down(c3, off);
    }
    __shared__ float sred[4][4];
    const int wave = tid >> 6;
    const int lane = tid & 63;
    if (lane == 0) {
        sred[wave][0] = c0; sred[wave][1] = c1;
        sred[wave][2] = c2; sred[wave][3] = c3;
    }
    __syncthreads();
    if (tid == 0) {
        const float coord = sred[0][0] + sred[1][0] + sred[2][0] + sred[3][0];
        const float conf  = sred[0][1] + sred[1][1] + sred[2][1] + sred[3][1];
        const float cls   = sred[0][2] + sred[1][2] + sred[2][2] + sred[3][2];
        const float nobj  = sred[0][3] + sred[1][3] + sred[2][3] + sred[3][3];
        out[0] = kLamCoord * (coord / (float)kB)
               + (conf / (float)kB)
               + cls / fmaxf(nobj, 1.f);
    }
}

extern "C" void kernel_launch(void* const* d_in, const int* in_sizes, int n_in,
                              void* d_out, int out_size, void* d_ws, size_t ws_size,
                              hipStream_t stream) {
    const float4* pred4 = (const float4*)d_in[0];
    const float4* tgt4  = (const float4*)d_in[1];
    float4* part = (float4*)d_ws;          // kBlocksM * 16 B = 8192 B
    float* out = (float*)d_out;

    phobia_main_kernel<<<kBlocksM, 256, 0, stream>>>(pred4, tgt4, part);
    phobia_reduce_kernel<<<1, 256, 0, stream>>>(part, out);
}